// Round 11
// baseline (306.541 us; speedup 1.0000x reference)
//
#include <hip/hip_runtime.h>
#include <stdint.h>

typedef unsigned short u16;
typedef uint8_t u8;
typedef __bf16 bf16x8 __attribute__((ext_vector_type(8)));
typedef float f32x4 __attribute__((ext_vector_type(4)));
typedef float f32x16 __attribute__((ext_vector_type(16)));
typedef long i64x2 __attribute__((ext_vector_type(2)));
typedef int i32x8 __attribute__((ext_vector_type(8)));

#define NTOK 8192
#define DD 512
#define CHK 512
#define NCH 16
#define KSPLIT 2
#define KLEN 4096
#define LOG2E 1.4426950408889634f
#define SCL 0.044194173824159216f          // 1/sqrt(512)
#define SCLL 0.063762069130835270f         // SCL * LOG2E

__device__ __forceinline__ u16 f2bf(float f) {
  union { float f; uint32_t u; } v; v.f = f;
  uint32_t r = v.u + 0x7FFFu + ((v.u >> 16) & 1u);
  return (u16)(r >> 16);
}

// DPP-based 16-lane (row) sum: stays on VALU pipe, avoids LDS-pipe shuffles.
template <int CTRL>
__device__ __forceinline__ float dppadd(float x) {
  int y = __builtin_amdgcn_update_dpp(0, __float_as_int(x), CTRL, 0xF, 0xF, true);
  return x + __int_as_float(y);
}
__device__ __forceinline__ float rowsum16(float x) {
  x = dppadd<0xB1>(x);    // quad_perm(1,0,3,2)
  x = dppadd<0x4E>(x);    // quad_perm(2,3,0,1)
  x = dppadd<0x141>(x);   // row_half_mirror
  x = dppadd<0x140>(x);   // row_mirror
  return x;
}

// async global->LDS, 16B per lane. LDS dest is wave-uniform base + lane*16.
typedef const __attribute__((address_space(1))) unsigned int* gas_t;
typedef __attribute__((address_space(3))) unsigned int* las_t;
__device__ __forceinline__ void gload16(const void* g, void* l) {
  __builtin_amdgcn_global_load_lds((gas_t)g, (las_t)l, 16, 0, 0);
}

// Pipeline fences.
// vm4bar (counted): kernels where EVERY wave issues exactly 4 loads/stage —
// measured win on qkv/outproj/gemm (uniform counts); measured LOSS on scores
// (Q-waves issue 5 -> over-wait on a fresh load).
__device__ __forceinline__ void vm4bar() {
  asm volatile("s_waitcnt vmcnt(4)\n\ts_barrier" ::: "memory");
}
// vm0bar: drain own loads + barrier (R2/R5 scores arrangement: rotated
// single-barrier pipeline — issue->wait window = one full compute phase).
__device__ __forceinline__ void vm0bar() {
  asm volatile("s_waitcnt vmcnt(0)\n\ts_barrier" ::: "memory");
}
__device__ __forceinline__ void barx() {
  asm volatile("s_barrier" ::: "memory");
}
// lgkm0 + sched_barrier(0): rule #18 — hipcc hoists register-only MFMA past inline-asm
// lgkmcnt despite the memory clobber; the sched_barrier is the actual fence.
__device__ __forceinline__ void lgkm0() {
  asm volatile("s_waitcnt lgkmcnt(0)" ::: "memory");
  __builtin_amdgcn_sched_barrier(0);
}

// k/token interleave within 64-groups: 8-byte group c -> (c&3)*2 + (c>>2).
// Makes a lane's two K=32 MFMA fragments (k=q*8.., k=32+q*8..) contiguous 16B.
// (used for qb8/kb8, consumed by scores' 16x16x32 frags)
__device__ __forceinline__ int ilv64(int p) {   // p in 0..63
  const int g = p >> 3;
  return (((g & 3) * 2) + (g >> 2)) * 8 + (p & 7);
}

// ---------------- prep: cast x->bf16 (+zero lsum/ticket), transpose 4 weights, cls q0 ----------------
__global__ void prep_kernel(const float* __restrict__ x, const float* __restrict__ Wq,
                            const float* __restrict__ Wk, const float* __restrict__ Wv,
                            const float* __restrict__ Wo, const float* __restrict__ bq,
                            u16* __restrict__ xb, u16* __restrict__ Wall, u16* __restrict__ WoT,
                            float* __restrict__ lsum, float* __restrict__ q0g,
                            unsigned int* __restrict__ ticket) {
  __shared__ float t[32][33];
  const int bid = blockIdx.x;
  const int tid = threadIdx.x;
  if (bid < 4096) {
    int i = bid * 256 + tid;
    if (bid < 32) lsum[bid * 256 + tid] = 0.f;
    if (bid == 0 && tid == 0) *ticket = 0u;
    float4 v = ((const float4*)x)[i];
    ushort4 o;
    o.x = f2bf(v.x); o.y = f2bf(v.y); o.z = f2bf(v.z); o.w = f2bf(v.w);
    ((ushort4*)xb)[i] = o;
  } else if (bid < 5120) {
    const int tt = bid - 4096;
    const int z = tt >> 8, idx = tt & 255;
    const float* W; u16* WT;
    if (z == 0)      { W = Wq; WT = Wall; }
    else if (z == 1) { W = Wk; WT = Wall + 512 * 512; }
    else if (z == 2) { W = Wv; WT = Wall + 2 * 512 * 512; }
    else             { W = Wo; WT = WoT; }
    const int n0 = (idx & 15) * 32, k0 = (idx >> 4) * 32;
    const int tx = tid & 31, ty = tid >> 5;  // 32 x 8
    #pragma unroll
    for (int i = 0; i < 4; i++)
      t[ty + 8 * i][tx] = W[(k0 + ty + 8 * i) * DD + n0 + tx];
    __syncthreads();
    #pragma unroll
    for (int i = 0; i < 4; i++)
      WT[(n0 + ty + 8 * i) * DD + k0 + tx] = f2bf(t[tx][ty + 8 * i]);
  } else {
    const int c = (bid - 5120) * 256 + tid;
    float acc = bq[c];
    #pragma unroll 8
    for (int i = 0; i < 512; i++) acc += x[i] * Wq[i * 512 + c];
    q0g[c] = acc;
  }
}

// ---------------- fused q/k/v projection: 256 thr, 128x128 tiles, counted-vmcnt dbuf ----------------
// grid (64, 13): y<12 GEMM (which = y>>2); y==12: cls_u folded in (x<9 active).
__launch_bounds__(256, 3)
__global__ void qkv_kernel(const u16* __restrict__ A, const u16* __restrict__ Wall,
                           const float* __restrict__ bq, const float* __restrict__ bk,
                           const float* __restrict__ bv, u8* __restrict__ qb8,
                           u8* __restrict__ kb8, u8* __restrict__ vT8,
                           const float* __restrict__ WkF, const float* __restrict__ bkF,
                           const float* __restrict__ q0g, float* __restrict__ uc) {
  __shared__ __align__(16) u16 As[2][128 * 32];
  __shared__ __align__(16) u16 Bs[2][128 * 32];
  const int tid = threadIdx.x;
  if (blockIdx.y == 12) {
    // ---- folded cls_u (exact fp32): uc = Wk @ q0 (+ bk . q0) ----
    if (blockIdx.x >= 9) return;
    float* q0 = (float*)As;     // reuse LDS
    q0[tid] = q0g[tid];
    q0[tid + 256] = q0g[tid + 256];
    __syncthreads();
    if (blockIdx.x < 8) {
      const int c = blockIdx.x * 64 + (tid >> 2), ii = tid & 3;
      float acc = 0.f;
      #pragma unroll 8
      for (int j = ii; j < 512; j += 4) acc += WkF[(size_t)c * 512 + j] * q0[j];
      acc += __shfl_xor(acc, 1, 64);
      acc += __shfl_xor(acc, 2, 64);
      if (ii == 0) uc[c] = acc;
    } else if (tid < 64) {
      float acc = 0.f;
      #pragma unroll 8
      for (int j = tid; j < 512; j += 64) acc += bkF[j] * q0[j];
      #pragma unroll
      for (int off = 1; off < 64; off <<= 1) acc += __shfl_xor(acc, off, 64);
      if (tid == 0) uc[512] = acc;
    }
    return;
  }
  const int m0 = blockIdx.x * 128;
  const int n0g = blockIdx.y * 128;
  const int which = blockIdx.y >> 2;
  const int n0 = n0g & 511;
  const int w = tid >> 6, lane = tid & 63, lm = lane & 15, quad = lane >> 4;
  const int wm = w & 1, wn = w >> 1;
  f32x4 acc[4][4] = {};
  const int soff = tid * 16;
  const int srow = soff >> 6;
  const int scol = soff & 63;
  const char* Ag = (const char*)A + ((size_t)(m0 + srow) * DD) * 2 + scol;
  const char* Bg = (const char*)Wall + ((size_t)(n0g + srow) * DD) * 2 + scol;
  char* Al = (char*)As + w * 1024;
  char* Bl = (char*)Bs + w * 1024;
  const size_t rs = (size_t)64 * DD * 2;

  auto stage = [&](int kk, int buf) {
    const char* ag = Ag + (size_t)kk * 2;
    const char* bg = Bg + (size_t)kk * 2;
    char* al = Al + buf * 8192;
    char* bl = Bl + buf * 8192;
    gload16(ag, al);
    gload16(ag + rs, al + 4096);
    gload16(bg, bl);
    gload16(bg + rs, bl + 4096);
  };

  stage(0, 0);
  for (int t = 0; t < 16; ++t) {
    const int cur = t & 1;
    if (t < 15) { stage((t + 1) * 32, cur ^ 1); vm4bar(); }
    else vm0bar();
    bf16x8 af[4], bfr[4];
    #pragma unroll
    for (int i = 0; i < 4; i++) af[i] = *(const bf16x8*)&As[cur][(wm * 64 + i * 16 + lm) * 32 + quad * 8];
    #pragma unroll
    for (int j = 0; j < 4; j++) bfr[j] = *(const bf16x8*)&Bs[cur][(wn * 64 + j * 16 + lm) * 32 + quad * 8];
    lgkm0();
    #pragma unroll
    for (int i = 0; i < 4; i++)
      #pragma unroll
      for (int j = 0; j < 4; j++)
        acc[i][j] = __builtin_amdgcn_mfma_f32_16x16x32_bf16(af[i], bfr[j], acc[i][j], 0, 0, 0);
    barx();
  }
  // ---- epilogue: LDS-staged permuted tile -> coalesced 16B global stores ----
  const float* bias = (which == 0) ? bq : (which == 1) ? bk : bv;
  u8* tile = (u8*)As;   // 16 KB = 128 x 128 bytes
  #pragma unroll
  for (int i = 0; i < 4; i++) {
    const int rl0 = wm * 64 + i * 16 + quad * 4;
    #pragma unroll
    for (int j = 0; j < 4; j++) {
      const int cl = wn * 64 + j * 16 + lm;
      const float bv_ = bias[n0 + cl];
      if (which == 2) {
        // tile[col][pi-local(token)]: pi(t) = (t&15)*4 + (t>>4) within 64-group
        #pragma unroll
        for (int r = 0; r < 4; r++) {
          const float val = acc[i][j][r] + bv_;
          uint32_t pk = __builtin_amdgcn_cvt_pk_fp8_f32(val, val, 0, false);
          const int rl = rl0 + r;
          const int t6 = rl & 63;
          const int tl = (rl & 64) | ((t6 & 15) * 4 + (t6 >> 4));
          tile[cl * 128 + tl] = (u8)(pk & 0xFF);
        }
      } else {
        // tile[row][ilv64-local(col)]
        const int icl = (cl & 64) | ilv64(cl & 63);
        #pragma unroll
        for (int r = 0; r < 4; r++) {
          const float val = acc[i][j][r] + bv_;
          uint32_t pk = __builtin_amdgcn_cvt_pk_fp8_f32(val, val, 0, false);
          tile[(rl0 + r) * 128 + icl] = (u8)(pk & 0xFF);
        }
      }
    }
  }
  __syncthreads();
  const int lrow = tid >> 1, half = tid & 1;
  const uint4* s4 = (const uint4*)(tile + lrow * 128 + half * 64);
  if (which == 2) {
    uint4* p = (uint4*)(vT8 + (size_t)(n0 + lrow) * NTOK + m0 + half * 64);
    #pragma unroll
    for (int k = 0; k < 4; k++) p[k] = s4[k];
  } else {
    u8* dst = (which == 0) ? qb8 : kb8;
    uint4* p = (uint4*)(dst + (size_t)(m0 + lrow) * DD + n0 + half * 64);
    #pragma unroll
    for (int k = 0; k < 4; k++) p[k] = s4[k];
  }
}

// ---------------- out projection + folded cls_scores/cls_softmax ----------------
// grid (64, 8): y<4 GEMM; y>=4: cls_scores block cb=(y-4)*64+x (256 blocks, 32 rows each).
// Last cls block to finish (device-scope ticket) runs the 256-thr cls softmax.
__launch_bounds__(256, 3)
__global__ void outproj_kernel(const u16* __restrict__ A, const u16* __restrict__ BT,
                               const float* __restrict__ bias, float* __restrict__ outp,
                               const float* __restrict__ resid, const float* __restrict__ uc,
                               float* __restrict__ s0, unsigned int* __restrict__ ticket) {
  __shared__ __align__(16) u16 As[2][128 * 32];
  __shared__ __align__(16) u16 Bs[2][128 * 32];
  const int tid = threadIdx.x;
  if (blockIdx.y >= 4) {
    // ---- folded cls_scores: s0[row] = (x[row].u + c0s) * SCL ----
    const int cb = (blockIdx.y - 4) * 64 + blockIdx.x;   // 0..255
    __shared__ float u[512];
    __shared__ float c0s;
    __shared__ int sOld;
    for (int i = tid; i < 512; i += 256) u[i] = uc[i];
    if (tid == 0) c0s = uc[512];
    __syncthreads();
    const int rowg = cb * 32 + (tid >> 3);
    const int ii = tid & 7;
    const float* xr = resid + (size_t)rowg * 512;
    float a2 = 0.f;
    for (int i = ii; i < 512; i += 8) a2 += xr[i] * u[i];
    a2 += __shfl_xor(a2, 1, 64);
    a2 += __shfl_xor(a2, 2, 64);
    a2 += __shfl_xor(a2, 4, 64);
    if (ii == 0) s0[rowg] = (a2 + c0s) * SCL;
    // release: own stores -> device scope, then block-ordered ticket
    __threadfence();
    __syncthreads();
    if (tid == 0) sOld = (int)atomicAdd(ticket, 1u);
    __syncthreads();
    if (sOld == 255) {
      // acquire: all 255 other blocks' s0 stores are device-visible
      __threadfence();
      __shared__ float lw2[16];
      const int wv = tid >> 6, lane = tid & 63;
      float vv[4][8];
      #pragma unroll
      for (int cc = 0; cc < 4; cc++) {
        const int ch = wv * 4 + cc;
        const float* sc = s0 + ch * 512;
        float m = -1e30f;
        #pragma unroll
        for (int j = 0; j < 8; j++) { vv[cc][j] = sc[lane * 8 + j]; m = fmaxf(m, vv[cc][j]); }
        for (int off = 1; off < 64; off <<= 1) m = fmaxf(m, __shfl_xor(m, off, 64));
        float z = 0.f;
        #pragma unroll
        for (int j = 0; j < 8; j++) { vv[cc][j] = expf(vv[cc][j] - m); z += vv[cc][j]; }
        for (int off = 1; off < 64; off <<= 1) z += __shfl_xor(z, off, 64);
        const float invz = 1.f / z;
        float l = 0.f;
        #pragma unroll
        for (int j = 0; j < 8; j++) { vv[cc][j] = expf(vv[cc][j] * invz); l += vv[cc][j]; }
        for (int off = 1; off < 64; off <<= 1) l += __shfl_xor(l, off, 64);
        if (lane == 0) lw2[ch] = l;
      }
      __syncthreads();
      float L = 0.f;
      #pragma unroll
      for (int i = 0; i < 16; i++) L += lw2[i];
      const float invL = 1.f / L;
      float* outc = outp + (size_t)NTOK * DD;
      #pragma unroll
      for (int cc = 0; cc < 4; cc++)
        #pragma unroll
        for (int j = 0; j < 8; j++)
          outc[(wv * 4 + cc) * 512 + lane * 8 + j] = vv[cc][j] * invL;
    }
    return;
  }
  const int m0 = blockIdx.x * 128, n0 = blockIdx.y * 128;
  const int w = tid >> 6, lane = tid & 63, lm = lane & 15, quad = lane >> 4;
  const int wm = w & 1, wn = w >> 1;
  f32x4 acc[4][4] = {};
  const int soff = tid * 16;
  const int srow = soff >> 6;
  const int scol = soff & 63;
  const char* Ag = (const char*)A + ((size_t)(m0 + srow) * DD) * 2 + scol;
  const char* Bg = (const char*)BT + ((size_t)(n0 + srow) * DD) * 2 + scol;
  char* Al = (char*)As + w * 1024;
  char* Bl = (char*)Bs + w * 1024;
  const size_t rs = (size_t)64 * DD * 2;

  auto stage = [&](int kk, int buf) {
    const char* ag = Ag + (size_t)kk * 2;
    const char* bg = Bg + (size_t)kk * 2;
    char* al = Al + buf * 8192;
    char* bl = Bl + buf * 8192;
    gload16(ag, al);
    gload16(ag + rs, al + 4096);
    gload16(bg, bl);
    gload16(bg + rs, bl + 4096);
  };

  stage(0, 0);
  for (int t = 0; t < 16; ++t) {
    const int cur = t & 1;
    if (t < 15) { stage((t + 1) * 32, cur ^ 1); vm4bar(); }
    else vm0bar();
    bf16x8 af[4], bfr[4];
    #pragma unroll
    for (int i = 0; i < 4; i++) af[i] = *(const bf16x8*)&As[cur][(wm * 64 + i * 16 + lm) * 32 + quad * 8];
    #pragma unroll
    for (int j = 0; j < 4; j++) bfr[j] = *(const bf16x8*)&Bs[cur][(wn * 64 + j * 16 + lm) * 32 + quad * 8];
    lgkm0();
    #pragma unroll
    for (int i = 0; i < 4; i++)
      #pragma unroll
      for (int j = 0; j < 4; j++)
        acc[i][j] = __builtin_amdgcn_mfma_f32_16x16x32_bf16(af[i], bfr[j], acc[i][j], 0, 0, 0);
    barx();
  }
  #pragma unroll
  for (int i = 0; i < 4; i++) {
    const int row0 = m0 + wm * 64 + i * 16 + quad * 4;
    #pragma unroll
    for (int j = 0; j < 4; j++) {
      const int col = n0 + wn * 64 + j * 16 + lm;
      const float bv = bias[col];
      #pragma unroll
      for (int r = 0; r < 4; r++) {
        const size_t idx = (size_t)(row0 + r) * DD + col;
        outp[idx] = acc[i][j][r] + bv + resid[idx];
      }
    }
  }
}

// ---------------- MX-fp8 PV GEMM: 256 thr, 128x128 tiles, BK=64, 32x32x64 scaled MFMA ----------------
// Unit E8M0 scales (0x7F = 2^0) => numerically identical to plain fp8 matmul at 2x rate.
// Lane holds 32 CONTIGUOUS K-bytes (row/col = lane&31, k-half = lane>>5) -> P8/vT8 carry
// pi(t)=(t&15)*4+(t>>4) within 64-token groups. C/D: col=lane&31, row=(r&3)+8*(r>>2)+4*kh.
template <int MODE>
__launch_bounds__(256, 3)
__global__ void gemm_pv_kernel(const u8* __restrict__ A, const u8* __restrict__ BT,
                               int K, void* __restrict__ outp,
                               const float* __restrict__ lsum) {
  __shared__ __align__(16) u8 As[2][128 * 64];
  __shared__ __align__(16) u8 Bs[2][128 * 64];
  const int m0 = blockIdx.x * 128, n0 = blockIdx.y * 128;
  const int tid = threadIdx.x;
  const int w = tid >> 6, lane = tid & 63;
  const int l31 = lane & 31, kh = lane >> 5;
  const int wm = w & 1, wn = w >> 1;
  f32x16 acc[2][2] = {};
  const int srow = tid >> 2;                                    // 0..63
  const int scol = ((tid & 3) ^ ((srow >> 1) & 3)) * 16;        // swizzled global chunk
  const size_t kbase = (size_t)blockIdx.z * (size_t)K;
  const u8* Ag = A + (size_t)(m0 + srow) * NTOK + kbase + scol;
  const u8* Bg = BT + (size_t)(n0 + srow) * NTOK + kbase + scol;
  u8* Al = (u8*)As + w * 1024;
  u8* Bl = (u8*)Bs + w * 1024;
  const size_t rs = (size_t)64 * NTOK;
  const int s_ = (l31 >> 1) & 3;
  const int c0 = ((kh * 2) ^ s_) * 16;
  const int c1 = ((kh * 2 + 1) ^ s_) * 16;

  auto stage = [&](int kk, int buf) {
    gload16(Ag + kk, Al + buf * 8192);
    gload16(Ag + kk + rs, Al + buf * 8192 + 4096);
    gload16(Bg + kk, Bl + buf * 8192);
    gload16(Bg + kk + rs, Bl + buf * 8192 + 4096);
  };

  stage(0, 0);
  int cur = 0;
  for (int kk = 0; kk < K; kk += 64) {
    if (kk + 64 < K) { stage(kk + 64, cur ^ 1); vm4bar(); }
    else vm0bar();
    i32x8 av[2], bv[2];
    #pragma unroll
    for (int g = 0; g < 2; g++) {
      const int ar = wm * 64 + g * 32 + l31;
      union { i32x8 v; struct { i64x2 lo; i64x2 hi; } p; } ua;
      ua.p.lo = *(const i64x2*)&As[cur][ar * 64 + c0];
      ua.p.hi = *(const i64x2*)&As[cur][ar * 64 + c1];
      av[g] = ua.v;
      const int br = wn * 64 + g * 32 + l31;
      union { i32x8 v; struct { i64x2 lo; i64x2 hi; } p; } ub;
      ub.p.lo = *(const i64x2*)&Bs[cur][br * 64 + c0];
      ub.p.hi = *(const i64x2*)&Bs[cur][br * 64 + c1];
      bv[g] = ub.v;
    }
    lgkm0();
    #pragma unroll
    for (int i = 0; i < 2; i++)
      #pragma unroll
      for (int j = 0; j < 2; j++)
        acc[i][j] = __builtin_amdgcn_mfma_scale_f32_32x32x64_f8f6f4(
            av[i], bv[j], acc[i][j], 0, 0, 0, 0x7F7F7F7F, 0, 0x7F7F7F7F);
    barx();
    cur ^= 1;
  }
  #pragma unroll
  for (int i = 0; i < 2; i++) {
    #pragma unroll
    for (int j = 0; j < 2; j++) {
      #pragma unroll
      for (int r = 0; r < 16; r++) {
        const int row = m0 + wm * 64 + i * 32 + (r & 3) + 8 * (r >> 2) + 4 * kh;
        const int col = n0 + wn * 64 + j * 32 + l31;
        if (MODE == 3) {
          ((u16*)outp)[(size_t)row * DD + col] = f2bf(acc[i][j][r] * (1.0f / lsum[row]));
        } else {
          float* po = (float*)outp + (size_t)blockIdx.z * NTOK * DD;
          po[(size_t)row * DD + col] = acc[i][j][r];
        }
      }
    }
  }
}

// ---------------- split-K PV reduce (2 parts): attnb = (p0 + p1) / lsum ----------------
__global__ void pv_reduce_kernel(const float* __restrict__ part, const float* __restrict__ lsum,
                                 u16* __restrict__ attnb) {
  const int idx = blockIdx.x * 256 + threadIdx.x;
  const int row = idx >> 7;
  const int c4 = (idx & 127) << 2;
  const float* p = part + (size_t)row * DD + c4;
  const size_t stride = (size_t)NTOK * DD;
  float4 a = *(const float4*)(p);
  float4 b = *(const float4*)(p + stride);
  const float inv = 1.0f / lsum[row];
  ushort4 o;
  o.x = f2bf((a.x + b.x) * inv);
  o.y = f2bf((a.y + b.y) * inv);
  o.z = f2bf((a.z + b.z) * inv);
  o.w = f2bf((a.w + b.w) * inv);
  *(ushort4*)(attnb + (size_t)row * DD + c4) = o;
}

// ---------------- scores: fp8 QK^T, 64 q-rows x 512-key chunk, 512 thr, BK=64 ----------------
// R2/R5 arrangement (best measured: 87 µs): rotated single-barrier pipeline.
// Phase-C P8 layout: pi(t)=(t&15)*4+(t>>4) within 64-groups (pbyte = wsl*64 + lm*4),
// feeding the MX-PV A-fragment (32 contiguous bytes per lane). vT8 carries the same pi.
__launch_bounds__(512, 4)
__global__ void scores_kernel(const u8* __restrict__ qb8, const u8* __restrict__ kb8,
                              u8* __restrict__ P8, float* __restrict__ lsum) {
  __shared__ __align__(16) u8 As[2][64 * 64];    // 2 x 4 KB
  __shared__ __align__(16) u8 Bs[2][512 * 64];   // 2 x 32 KB
  __shared__ float hS[8][64], hP[8][64], hZ[64];
  const int m0 = blockIdx.x * 64;
  const int c = blockIdx.y;
  const int tid = threadIdx.x;
  const int w = tid >> 6, lane = tid & 63, lm = lane & 15, quad = lane >> 4;
  const int wsl = w;                          // key slice 0..7 (64 keys each)
  f32x4 s[4][4] = {};
  const int srA = tid >> 2;                                   // A: 0..63 ; B: 0..127
  const int scS = ((tid & 3) ^ ((srA >> 1) & 3)) * 16;        // staging swizzle
  const u8* Qg = qb8 + (size_t)(m0 + srA) * DD + scS;         // deref'd only for tid<256
  const u8* Kg = kb8 + (size_t)(c * CHK + srA) * DD + scS;
  u8* Al = (u8*)As + w * 1024;                // waves 0..3 stage A (4 KB)
  u8* Bl = (u8*)Bs + w * 1024;                // all 8 waves stage B (4 x 8 KB slabs)
  const int csel = ((quad ^ ((lm >> 1) & 3)) * 16);

  auto stage = [&](int kk, int buf) {
    u8* al = Al + buf * 4096;
    u8* bl = Bl + buf * 32768;
    if (tid < 256) gload16(Qg + kk, al);
    gload16(Kg + kk, bl);
    gload16(Kg + kk + (size_t)128 * DD, bl + 8192);
    gload16(Kg + kk + (size_t)256 * DD, bl + 16384);
    gload16(Kg + kk + (size_t)384 * DD, bl + 24576);
  };

  stage(0, 0);
  vm0bar();
  #pragma unroll
  for (int t = 0; t < 8; ++t) {
    const int cur = t & 1;
    if (t < 7) stage((t + 1) * 64, cur ^ 1);
    i64x2 afv[4], bfv[4];
    #pragma unroll
    for (int i = 0; i < 4; i++)
      afv[i] = *(const i64x2*)&As[cur][(i * 16 + lm) * 64 + csel];
    #pragma unroll
    for (int j = 0; j < 4; j++)
      bfv[j] = *(const i64x2*)&Bs[cur][(wsl * 64 + j * 16 + lm) * 64 + csel];
    lgkm0();
    __builtin_amdgcn_s_setprio(1);
    #pragma unroll
    for (int i = 0; i < 4; i++)
      #pragma unroll
      for (int j = 0; j < 4; j++) {
        s[i][j] = __builtin_amdgcn_mfma_f32_16x16x32_fp8_fp8(afv[i].x, bfv[j].x, s[i][j], 0, 0, 0);
        s[i][j] = __builtin_amdgcn_mfma_f32_16x16x32_fp8_fp8(afv[i].y, bfv[j].y, s[i][j], 0, 0, 0);
      }
    __builtin_amdgcn_s_setprio(0);
    vm0bar();   // next-tile loads landed while MFMAs ran
  }
  // ---- phase A: e = exp2(s_raw * SCL*LOG2E); per-wave (64-col) partial row sums (DPP) ----
  #pragma unroll
  for (int i = 0; i < 4; i++) {
    #pragma unroll
    for (int reg = 0; reg < 4; reg++) {
      float z = 0.f;
      #pragma unroll
      for (int j = 0; j < 4; j++) {
        float e = exp2f(s[i][j][reg] * SCLL);
        s[i][j][reg] = e;
        z += e;
      }
      z = rowsum16(z);
      if (lm == 0) hS[wsl][i * 16 + quad * 4 + reg] = z;
    }
  }
  __syncthreads();
  // ---- phase B: row totals -> hZ = LOG2E / Z ----
  if (tid < 64) {
    float t = 0.f;
    #pragma unroll
    for (int w2 = 0; w2 < 8; w2++) t += hS[w2][tid];
    hZ[tid] = LOG2E / t;
  }
  __syncthreads();
  // ---- phase C: p = exp2(e * LOG2E/Z); fp8 packed store in pi layout; partial l ----
  const int pbyte = wsl * 64 + lm * 4;
  #pragma unroll
  for (int i = 0; i < 4; i++) {
    #pragma unroll
    for (int reg = 0; reg < 4; reg++) {
      const int rl = i * 16 + quad * 4 + reg;
      const float iz = hZ[rl];
      const float p0 = exp2f(s[i][0][reg] * iz);
      const float p1 = exp2f(s[i][1][reg] * iz);
      const float p2 = exp2f(s[i][2][reg] * iz);
      const float p3 = exp2f(s[i][3][reg] * iz);
      float zp = (p0 + p1) + (p2 + p3);
      zp = rowsum16(zp);
      if (lm == 0) hP[wsl][rl] = zp;
      uint32_t o = __builtin_amdgcn_cvt_pk_fp8_f32(p0, p1, 0, false);
      o = __builtin_amdgcn_cvt_pk_fp8_f32(p2, p3, o, true);
      *(uint32_t*)(P8 + (size_t)(m0 + rl) * NTOK + c * CHK + pbyte) = o;
    }
  }
  __syncthreads();
  if (tid < 64) {
    float t = 0.f;
    #pragma unroll
    for (int w2 = 0; w2 < 8; w2++) t += hP[w2][tid];
    atomicAdd(&lsum[m0 + tid], t);
  }
}

extern "C" void kernel_launch(void* const* d_in, const int* in_sizes, int n_in,
                              void* d_out, int out_size, void* d_ws, size_t ws_size,
                              hipStream_t stream) {
  const float* x  = (const float*)d_in[0];
  const float* Wq = (const float*)d_in[1];
  const float* bq = (const float*)d_in[2];
  const float* Wk = (const float*)d_in[3];
  const float* bk = (const float*)d_in[4];
  const float* Wv = (const float*)d_in[5];
  const float* bv = (const float*)d_in[6];
  const float* Wo = (const float*)d_in[7];
  const float* bo = (const float*)d_in[8];
  float* out = (float*)d_out;

  char* ws = (char*)d_ws;
  u16* xb    = (u16*)(ws);                  // 8 MB
  u16* Wall  = (u16*)(ws + 8388608);        // 1.5 MB
  u16* WoT   = (u16*)(ws + 9961472);        // 512 KB
  u8*  qb8   = (u8*)(ws + 10485760);        // 4 MB fp8 (k-interleaved)
  u8*  kb8   = (u8*)(ws + 14680064);        // 4 MB fp8 (k-interleaved)
  u8*  vT8   = (u8*)(ws + 18874368);        // 4 MB fp8 (pi-perm tokens)
  u16* attnb = (u16*)(ws + 23068672);       // 8 MB
  float* q0g = (float*)(ws + 31457280);     // 512 f
  unsigned int* ticket = (unsigned int*)(ws + 31460352);  // 1 u32
  float* uc  = (float*)(ws + 31461376);     // 513 f
  float* s0  = (float*)(ws + 31465472);     // 8192 f
  float* lsum= (float*)(ws + 31498240);     // 8192 f
  u8*  P8    = (u8*)(ws + 31531008);        // 64 MB fp8 (pi-perm token cols)
  float* part= (float*)(ws + 98639872);     // 2 x 16 MB
  const size_t need_full = 98639872ULL + (size_t)KSPLIT * NTOK * DD * 4ULL;

  prep_kernel<<<5122, 256, 0, stream>>>(x, Wq, Wk, Wv, Wo, bq, xb, Wall, WoT, lsum, q0g, ticket);

  qkv_kernel<<<dim3(NTOK / 128, 13), 256, 0, stream>>>(xb, Wall, bq, bk, bv, qb8, kb8, vT8,
                                                       Wk, bk, q0g, uc);

  scores_kernel<<<dim3(NTOK / 64, NCH), 512, 0, stream>>>(qb8, kb8, P8, lsum);

  if (ws_size >= need_full) {
    gemm_pv_kernel<4><<<dim3(NTOK / 128, DD / 128, KSPLIT), 256, 0, stream>>>(
        P8, vT8, KLEN, part, nullptr);
    pv_reduce_kernel<<<NTOK * DD / 4 / 256, 256, 0, stream>>>(part, lsum, attnb);
  } else {
    gemm_pv_kernel<3><<<dim3(NTOK / 128, DD / 128), 256, 0, stream>>>(
        P8, vT8, NTOK, attnb, lsum);
  }

  outproj_kernel<<<dim3(NTOK / 128, 8), 256, 0, stream>>>(attnb, WoT, bo, out, x, uc, s0, ticket);
}

// Round 12
// 299.240 us; speedup vs baseline: 1.0244x; 1.0244x over previous
//
#include <hip/hip_runtime.h>
#include <stdint.h>

typedef unsigned short u16;
typedef uint8_t u8;
typedef __bf16 bf16x8 __attribute__((ext_vector_type(8)));
typedef float f32x4 __attribute__((ext_vector_type(4)));
typedef long i64x2 __attribute__((ext_vector_type(2)));

#define NTOK 8192
#define DD 512
#define CHK 512
#define NCH 16
#define KSPLIT 4
#define KLEN 2048
#define LOG2E 1.4426950408889634f
#define SCL 0.044194173824159216f          // 1/sqrt(512)
#define SCLL 0.063762069130835270f         // SCL * LOG2E

__device__ __forceinline__ u16 f2bf(float f) {
  union { float f; uint32_t u; } v; v.f = f;
  uint32_t r = v.u + 0x7FFFu + ((v.u >> 16) & 1u);
  return (u16)(r >> 16);
}

// DPP-based 16-lane (row) sum: stays on VALU pipe, avoids LDS-pipe shuffles.
template <int CTRL>
__device__ __forceinline__ float dppadd(float x) {
  int y = __builtin_amdgcn_update_dpp(0, __float_as_int(x), CTRL, 0xF, 0xF, true);
  return x + __int_as_float(y);
}
__device__ __forceinline__ float rowsum16(float x) {
  x = dppadd<0xB1>(x);    // quad_perm(1,0,3,2)
  x = dppadd<0x4E>(x);    // quad_perm(2,3,0,1)
  x = dppadd<0x141>(x);   // row_half_mirror
  x = dppadd<0x140>(x);   // row_mirror
  return x;
}

// async global->LDS, 16B per lane. LDS dest is wave-uniform base + lane*16.
typedef const __attribute__((address_space(1))) unsigned int* gas_t;
typedef __attribute__((address_space(3))) unsigned int* las_t;
__device__ __forceinline__ void gload16(const void* g, void* l) {
  __builtin_amdgcn_global_load_lds((gas_t)g, (las_t)l, 16, 0, 0);
}

// Pipeline fences.
// vm4bar (counted): kernels where EVERY wave issues exactly 4 loads/stage —
// measured win on qkv/outproj/gemm (uniform counts); measured LOSS on scores
// (Q-waves issue 5 -> over-wait on a fresh load).
__device__ __forceinline__ void vm4bar() {
  asm volatile("s_waitcnt vmcnt(4)\n\ts_barrier" ::: "memory");
}
// vm0bar: drain own loads + barrier (R2/R5 scores arrangement: rotated
// single-barrier pipeline — issue->wait window = one full compute phase).
__device__ __forceinline__ void vm0bar() {
  asm volatile("s_waitcnt vmcnt(0)\n\ts_barrier" ::: "memory");
}
__device__ __forceinline__ void barx() {
  asm volatile("s_barrier" ::: "memory");
}
// lgkm0 + sched_barrier(0): rule #18 — hipcc hoists register-only MFMA past inline-asm
// lgkmcnt despite the memory clobber; the sched_barrier is the actual fence.
__device__ __forceinline__ void lgkm0() {
  asm volatile("s_waitcnt lgkmcnt(0)" ::: "memory");
  __builtin_amdgcn_sched_barrier(0);
}

// k/token interleave within 64-groups: 8-byte group c -> (c&3)*2 + (c>>2).
// Makes a lane's two K=32 MFMA fragments (k=q*8.., k=32+q*8..) contiguous 16B.
__device__ __forceinline__ int ilv64(int p) {   // p in 0..63
  const int g = p >> 3;
  return (((g & 3) * 2) + (g >> 2)) * 8 + (p & 7);
}

// ---------------- prep: cast x->bf16 (+zero lsum), transpose 4 weights, cls q0 ----------------
__global__ void prep_kernel(const float* __restrict__ x, const float* __restrict__ Wq,
                            const float* __restrict__ Wk, const float* __restrict__ Wv,
                            const float* __restrict__ Wo, const float* __restrict__ bq,
                            u16* __restrict__ xb, u16* __restrict__ Wall, u16* __restrict__ WoT,
                            float* __restrict__ lsum, float* __restrict__ q0g) {
  __shared__ float t[32][33];
  const int bid = blockIdx.x;
  const int tid = threadIdx.x;
  if (bid < 4096) {
    int i = bid * 256 + tid;
    if (bid < 32) lsum[bid * 256 + tid] = 0.f;
    float4 v = ((const float4*)x)[i];
    ushort4 o;
    o.x = f2bf(v.x); o.y = f2bf(v.y); o.z = f2bf(v.z); o.w = f2bf(v.w);
    ((ushort4*)xb)[i] = o;
  } else if (bid < 5120) {
    const int tt = bid - 4096;
    const int z = tt >> 8, idx = tt & 255;
    const float* W; u16* WT;
    if (z == 0)      { W = Wq; WT = Wall; }
    else if (z == 1) { W = Wk; WT = Wall + 512 * 512; }
    else if (z == 2) { W = Wv; WT = Wall + 2 * 512 * 512; }
    else             { W = Wo; WT = WoT; }
    const int n0 = (idx & 15) * 32, k0 = (idx >> 4) * 32;
    const int tx = tid & 31, ty = tid >> 5;  // 32 x 8
    #pragma unroll
    for (int i = 0; i < 4; i++)
      t[ty + 8 * i][tx] = W[(k0 + ty + 8 * i) * DD + n0 + tx];
    __syncthreads();
    #pragma unroll
    for (int i = 0; i < 4; i++)
      WT[(n0 + ty + 8 * i) * DD + k0 + tx] = f2bf(t[tx][ty + 8 * i]);
  } else {
    const int c = (bid - 5120) * 256 + tid;
    float acc = bq[c];
    #pragma unroll 8
    for (int i = 0; i < 512; i++) acc += x[i] * Wq[i * 512 + c];
    q0g[c] = acc;
  }
}

// ---------------- fused q/k/v projection: 256 thr, 128x128 tiles, counted-vmcnt dbuf ----------------
// by: 0..11; which = by>>2 (0=q fp8 k-interleaved, 1=k fp8 k-interleaved, 2=v fp8 T+fperm)
// R9: epilogue stages the permuted fp8 tile in LDS (16 KB, reuses As) then writes
// global as 4x dwordx4/thread. ilv64/fperm are bijections within 64-token groups, so
// each output row (q/k) / col (v) of the 128x128 tile is a contiguous 128B run.
// Replaces 64 scattered 1-byte global stores per thread (4.2M byte-stores/launch).
__launch_bounds__(256, 3)
__global__ void qkv_kernel(const u16* __restrict__ A, const u16* __restrict__ Wall,
                           const float* __restrict__ bq, const float* __restrict__ bk,
                           const float* __restrict__ bv, u8* __restrict__ qb8,
                           u8* __restrict__ kb8, u8* __restrict__ vT8) {
  __shared__ __align__(16) u16 As[2][128 * 32];
  __shared__ __align__(16) u16 Bs[2][128 * 32];
  const int m0 = blockIdx.x * 128;
  const int n0g = blockIdx.y * 128;
  const int which = blockIdx.y >> 2;
  const int n0 = n0g & 511;
  const int tid = threadIdx.x;
  const int w = tid >> 6, lane = tid & 63, lm = lane & 15, quad = lane >> 4;
  const int wm = w & 1, wn = w >> 1;
  f32x4 acc[4][4] = {};
  const int soff = tid * 16;
  const int srow = soff >> 6;
  const int scol = soff & 63;
  const char* Ag = (const char*)A + ((size_t)(m0 + srow) * DD) * 2 + scol;
  const char* Bg = (const char*)Wall + ((size_t)(n0g + srow) * DD) * 2 + scol;
  char* Al = (char*)As + w * 1024;
  char* Bl = (char*)Bs + w * 1024;
  const size_t rs = (size_t)64 * DD * 2;

  auto stage = [&](int kk, int buf) {
    const char* ag = Ag + (size_t)kk * 2;
    const char* bg = Bg + (size_t)kk * 2;
    char* al = Al + buf * 8192;
    char* bl = Bl + buf * 8192;
    gload16(ag, al);
    gload16(ag + rs, al + 4096);
    gload16(bg, bl);
    gload16(bg + rs, bl + 4096);
  };

  stage(0, 0);
  for (int t = 0; t < 16; ++t) {
    const int cur = t & 1;
    if (t < 15) { stage((t + 1) * 32, cur ^ 1); vm4bar(); }
    else vm0bar();
    bf16x8 af[4], bfr[4];
    #pragma unroll
    for (int i = 0; i < 4; i++) af[i] = *(const bf16x8*)&As[cur][(wm * 64 + i * 16 + lm) * 32 + quad * 8];
    #pragma unroll
    for (int j = 0; j < 4; j++) bfr[j] = *(const bf16x8*)&Bs[cur][(wn * 64 + j * 16 + lm) * 32 + quad * 8];
    lgkm0();
    #pragma unroll
    for (int i = 0; i < 4; i++)
      #pragma unroll
      for (int j = 0; j < 4; j++)
        acc[i][j] = __builtin_amdgcn_mfma_f32_16x16x32_bf16(af[i], bfr[j], acc[i][j], 0, 0, 0);
    barx();
  }
  // ---- epilogue: LDS-staged permuted tile -> coalesced 16B global stores ----
  // safe to reuse As: every wave drained its ds_reads (lgkm0) before the final barx.
  const float* bias = (which == 0) ? bq : (which == 1) ? bk : bv;
  u8* tile = (u8*)As;   // 16 KB = 128 x 128 bytes
  #pragma unroll
  for (int i = 0; i < 4; i++) {
    const int rl0 = wm * 64 + i * 16 + quad * 4;
    #pragma unroll
    for (int j = 0; j < 4; j++) {
      const int cl = wn * 64 + j * 16 + lm;
      const float bv_ = bias[n0 + cl];
      if (which == 2) {
        // tile[col][fperm-local(token)]
        #pragma unroll
        for (int r = 0; r < 4; r++) {
          const float val = acc[i][j][r] + bv_;
          uint32_t pk = __builtin_amdgcn_cvt_pk_fp8_f32(val, val, 0, false);
          const int rl = rl0 + r;
          const int tl = (rl & 64) | ilv64(((rl & 15) << 2) | ((rl >> 4) & 3));
          tile[cl * 128 + tl] = (u8)(pk & 0xFF);
        }
      } else {
        // tile[row][ilv64-local(col)]
        const int icl = (cl & 64) | ilv64(cl & 63);
        #pragma unroll
        for (int r = 0; r < 4; r++) {
          const float val = acc[i][j][r] + bv_;
          uint32_t pk = __builtin_amdgcn_cvt_pk_fp8_f32(val, val, 0, false);
          tile[(rl0 + r) * 128 + icl] = (u8)(pk & 0xFF);
        }
      }
    }
  }
  __syncthreads();
  const int lrow = tid >> 1, half = tid & 1;
  const uint4* s4 = (const uint4*)(tile + lrow * 128 + half * 64);
  if (which == 2) {
    uint4* p = (uint4*)(vT8 + (size_t)(n0 + lrow) * NTOK + m0 + half * 64);
    #pragma unroll
    for (int k = 0; k < 4; k++) p[k] = s4[k];
  } else {
    u8* dst = (which == 0) ? qb8 : kb8;
    uint4* p = (uint4*)(dst + (size_t)(m0 + lrow) * DD + n0 + half * 64);
    #pragma unroll
    for (int k = 0; k < 4; k++) p[k] = s4[k];
  }
}

// ---------------- out projection: 256 thr, 128x128 tiles, counted-vmcnt dbuf ----------------
__launch_bounds__(256, 3)
__global__ void outproj_kernel(const u16* __restrict__ A, const u16* __restrict__ BT,
                               const float* __restrict__ bias, float* __restrict__ outp,
                               const float* __restrict__ resid) {
  __shared__ __align__(16) u16 As[2][128 * 32];
  __shared__ __align__(16) u16 Bs[2][128 * 32];
  const int m0 = blockIdx.x * 128, n0 = blockIdx.y * 128;
  const int tid = threadIdx.x;
  const int w = tid >> 6, lane = tid & 63, lm = lane & 15, quad = lane >> 4;
  const int wm = w & 1, wn = w >> 1;
  f32x4 acc[4][4] = {};
  const int soff = tid * 16;
  const int srow = soff >> 6;
  const int scol = soff & 63;
  const char* Ag = (const char*)A + ((size_t)(m0 + srow) * DD) * 2 + scol;
  const char* Bg = (const char*)BT + ((size_t)(n0 + srow) * DD) * 2 + scol;
  char* Al = (char*)As + w * 1024;
  char* Bl = (char*)Bs + w * 1024;
  const size_t rs = (size_t)64 * DD * 2;

  auto stage = [&](int kk, int buf) {
    const char* ag = Ag + (size_t)kk * 2;
    const char* bg = Bg + (size_t)kk * 2;
    char* al = Al + buf * 8192;
    char* bl = Bl + buf * 8192;
    gload16(ag, al);
    gload16(ag + rs, al + 4096);
    gload16(bg, bl);
    gload16(bg + rs, bl + 4096);
  };

  stage(0, 0);
  for (int t = 0; t < 16; ++t) {
    const int cur = t & 1;
    if (t < 15) { stage((t + 1) * 32, cur ^ 1); vm4bar(); }
    else vm0bar();
    bf16x8 af[4], bfr[4];
    #pragma unroll
    for (int i = 0; i < 4; i++) af[i] = *(const bf16x8*)&As[cur][(wm * 64 + i * 16 + lm) * 32 + quad * 8];
    #pragma unroll
    for (int j = 0; j < 4; j++) bfr[j] = *(const bf16x8*)&Bs[cur][(wn * 64 + j * 16 + lm) * 32 + quad * 8];
    lgkm0();
    #pragma unroll
    for (int i = 0; i < 4; i++)
      #pragma unroll
      for (int j = 0; j < 4; j++)
        acc[i][j] = __builtin_amdgcn_mfma_f32_16x16x32_bf16(af[i], bfr[j], acc[i][j], 0, 0, 0);
    barx();
  }
  #pragma unroll
  for (int i = 0; i < 4; i++) {
    const int row0 = m0 + wm * 64 + i * 16 + quad * 4;
    #pragma unroll
    for (int j = 0; j < 4; j++) {
      const int col = n0 + wn * 64 + j * 16 + lm;
      const float bv = bias[col];
      #pragma unroll
      for (int r = 0; r < 4; r++) {
        const size_t idx = (size_t)(row0 + r) * DD + col;
        outp[idx] = acc[i][j][r] + bv + resid[idx];
      }
    }
  }
}

// ---------------- fp8 PV GEMM: 256 thr, 128x128 tiles, BK=64, counted-vmcnt dbuf ----------------
// contraction dim (tokens) interleaved via fperm on both P8 and vT8
// MODE 3: bf16 out scaled by 1/lsum[row]; MODE 4: fp32 partial, K-range by blockIdx.z
template <int MODE>
__launch_bounds__(256, 3)
__global__ void gemm_fp8_kernel(const u8* __restrict__ A, const u8* __restrict__ BT,
                                int K, int lda, int ldb, void* __restrict__ outp,
                                const float* __restrict__ lsum) {
  __shared__ __align__(16) u8 As[2][128 * 64];
  __shared__ __align__(16) u8 Bs[2][128 * 64];
  const int m0 = blockIdx.x * 128, n0 = blockIdx.y * 128;
  const int tid = threadIdx.x;
  const int w = tid >> 6, lane = tid & 63, lm = lane & 15, quad = lane >> 4;
  const int wm = w & 1, wn = w >> 1;
  f32x4 acc[4][4] = {};
  const int srow = tid >> 2;                                    // 0..63
  const int scol = ((tid & 3) ^ ((srow >> 1) & 3)) * 16;        // swizzled global chunk
  const size_t kbase = (MODE == 4) ? (size_t)blockIdx.z * (size_t)K : 0;
  const u8* Ag = A + (size_t)(m0 + srow) * lda + kbase + scol;
  const u8* Bg = BT + (size_t)(n0 + srow) * ldb + kbase + scol;
  u8* Al = (u8*)As + w * 1024;
  u8* Bl = (u8*)Bs + w * 1024;
  const size_t ars = (size_t)64 * lda;
  const size_t brs = (size_t)64 * ldb;
  const int csel = ((quad ^ ((lm >> 1) & 3)) * 16);

  auto stage = [&](int kk, int buf) {
    const u8* ag = Ag + kk;
    const u8* bg = Bg + kk;
    u8* al = Al + buf * 8192;
    u8* bl = Bl + buf * 8192;
    gload16(ag, al);
    gload16(ag + ars, al + 4096);
    gload16(bg, bl);
    gload16(bg + brs, bl + 4096);
  };

  stage(0, 0);
  int cur = 0;
  for (int kk = 0; kk < K; kk += 64) {
    if (kk + 64 < K) { stage(kk + 64, cur ^ 1); vm4bar(); }
    else vm0bar();
    i64x2 afv[4], bfv[4];
    #pragma unroll
    for (int i = 0; i < 4; i++)
      afv[i] = *(const i64x2*)&As[cur][(wm * 64 + i * 16 + lm) * 64 + csel];
    #pragma unroll
    for (int j = 0; j < 4; j++)
      bfv[j] = *(const i64x2*)&Bs[cur][(wn * 64 + j * 16 + lm) * 64 + csel];
    lgkm0();
    #pragma unroll
    for (int i = 0; i < 4; i++)
      #pragma unroll
      for (int j = 0; j < 4; j++) {
        acc[i][j] = __builtin_amdgcn_mfma_f32_16x16x32_fp8_fp8(afv[i].x, bfv[j].x, acc[i][j], 0, 0, 0);
        acc[i][j] = __builtin_amdgcn_mfma_f32_16x16x32_fp8_fp8(afv[i].y, bfv[j].y, acc[i][j], 0, 0, 0);
      }
    barx();
    cur ^= 1;
  }
  #pragma unroll
  for (int i = 0; i < 4; i++) {
    const int row0 = m0 + wm * 64 + i * 16 + quad * 4;
    float li[4];
    if (MODE == 3) {
      #pragma unroll
      for (int r = 0; r < 4; r++) li[r] = 1.0f / lsum[row0 + r];
    }
    #pragma unroll
    for (int j = 0; j < 4; j++) {
      const int col = n0 + wn * 64 + j * 16 + lm;
      if (MODE == 3) {
        #pragma unroll
        for (int r = 0; r < 4; r++)
          ((u16*)outp)[(size_t)(row0 + r) * DD + col] = f2bf(acc[i][j][r] * li[r]);
      } else {
        float* po = (float*)outp + (size_t)blockIdx.z * NTOK * DD;
        #pragma unroll
        for (int r = 0; r < 4; r++)
          po[(size_t)(row0 + r) * DD + col] = acc[i][j][r];
      }
    }
  }
}

// ---------------- split-K PV reduce (4 parts): attnb = (sum parts) / lsum ----------------
__global__ void pv_reduce_kernel(const float* __restrict__ part, const float* __restrict__ lsum,
                                 u16* __restrict__ attnb) {
  const int idx = blockIdx.x * 256 + threadIdx.x;
  const int row = idx >> 7;
  const int c4 = (idx & 127) << 2;
  const float* p = part + (size_t)row * DD + c4;
  const size_t stride = (size_t)NTOK * DD;
  float4 a = *(const float4*)(p);
  float4 b = *(const float4*)(p + stride);
  float4 c = *(const float4*)(p + 2 * stride);
  float4 d = *(const float4*)(p + 3 * stride);
  const float inv = 1.0f / lsum[row];
  ushort4 o;
  o.x = f2bf((a.x + b.x + c.x + d.x) * inv);
  o.y = f2bf((a.y + b.y + c.y + d.y) * inv);
  o.z = f2bf((a.z + b.z + c.z + d.z) * inv);
  o.w = f2bf((a.w + b.w + c.w + d.w) * inv);
  *(ushort4*)(attnb + (size_t)row * DD + c4) = o;
}

// ---------------- scores: fp8 QK^T, 64 q-rows x 512-key chunk, 512 thr, BK=64 ----------------
// R2/R5 arrangement (best measured: 87 µs): rotated single-barrier pipeline —
// stage(t+1) at top, vmcnt(0)+barrier at bottom; issue->wait window = one full
// compute phase, one barrier/iter.
__launch_bounds__(512, 4)
__global__ void scores_kernel(const u8* __restrict__ qb8, const u8* __restrict__ kb8,
                              u8* __restrict__ P8, float* __restrict__ lsum) {
  __shared__ __align__(16) u8 As[2][64 * 64];    // 2 x 4 KB
  __shared__ __align__(16) u8 Bs[2][512 * 64];   // 2 x 32 KB
  __shared__ float hS[8][64], hP[8][64], hZ[64];
  const int m0 = blockIdx.x * 64;
  const int c = blockIdx.y;
  const int tid = threadIdx.x;
  const int w = tid >> 6, lane = tid & 63, lm = lane & 15, quad = lane >> 4;
  const int wsl = w;                          // key slice 0..7 (64 keys each)
  f32x4 s[4][4] = {};
  const int srA = tid >> 2;                                   // A: 0..63 ; B: 0..127
  const int scS = ((tid & 3) ^ ((srA >> 1) & 3)) * 16;        // staging swizzle
  const u8* Qg = qb8 + (size_t)(m0 + srA) * DD + scS;         // deref'd only for tid<256
  const u8* Kg = kb8 + (size_t)(c * CHK + srA) * DD + scS;
  u8* Al = (u8*)As + w * 1024;                // waves 0..3 stage A (4 KB)
  u8* Bl = (u8*)Bs + w * 1024;                // all 8 waves stage B (4 x 8 KB slabs)
  const int csel = ((quad ^ ((lm >> 1) & 3)) * 16);

  auto stage = [&](int kk, int buf) {
    u8* al = Al + buf * 4096;
    u8* bl = Bl + buf * 32768;
    if (tid < 256) gload16(Qg + kk, al);
    gload16(Kg + kk, bl);
    gload16(Kg + kk + (size_t)128 * DD, bl + 8192);
    gload16(Kg + kk + (size_t)256 * DD, bl + 16384);
    gload16(Kg + kk + (size_t)384 * DD, bl + 24576);
  };

  stage(0, 0);
  vm0bar();
  #pragma unroll
  for (int t = 0; t < 8; ++t) {
    const int cur = t & 1;
    if (t < 7) stage((t + 1) * 64, cur ^ 1);
    i64x2 afv[4], bfv[4];
    #pragma unroll
    for (int i = 0; i < 4; i++)
      afv[i] = *(const i64x2*)&As[cur][(i * 16 + lm) * 64 + csel];
    #pragma unroll
    for (int j = 0; j < 4; j++)
      bfv[j] = *(const i64x2*)&Bs[cur][(wsl * 64 + j * 16 + lm) * 64 + csel];
    lgkm0();
    __builtin_amdgcn_s_setprio(1);
    #pragma unroll
    for (int i = 0; i < 4; i++)
      #pragma unroll
      for (int j = 0; j < 4; j++) {
        s[i][j] = __builtin_amdgcn_mfma_f32_16x16x32_fp8_fp8(afv[i].x, bfv[j].x, s[i][j], 0, 0, 0);
        s[i][j] = __builtin_amdgcn_mfma_f32_16x16x32_fp8_fp8(afv[i].y, bfv[j].y, s[i][j], 0, 0, 0);
      }
    __builtin_amdgcn_s_setprio(0);
    vm0bar();   // next-tile loads landed while MFMAs ran
  }
  // ---- phase A: e = exp2(s_raw * SCL*LOG2E); per-wave (64-col) partial row sums (DPP) ----
  #pragma unroll
  for (int i = 0; i < 4; i++) {
    #pragma unroll
    for (int reg = 0; reg < 4; reg++) {
      float z = 0.f;
      #pragma unroll
      for (int j = 0; j < 4; j++) {
        float e = exp2f(s[i][j][reg] * SCLL);
        s[i][j][reg] = e;
        z += e;
      }
      z = rowsum16(z);
      if (lm == 0) hS[wsl][i * 16 + quad * 4 + reg] = z;
    }
  }
  __syncthreads();
  // ---- phase B: row totals -> hZ = LOG2E / Z ----
  if (tid < 64) {
    float t = 0.f;
    #pragma unroll
    for (int w2 = 0; w2 < 8; w2++) t += hS[w2][tid];
    hZ[tid] = LOG2E / t;
  }
  __syncthreads();
  // ---- phase C: p = exp2(e * LOG2E/Z); fp8 packed store in fperm layout; partial l ----
  const int newc = ((lm >> 1) & 3) * 2 + (lm >> 3);
  const int pbyte = wsl * 64 + newc * 8 + (lm & 1) * 4;
  #pragma unroll
  for (int i = 0; i < 4; i++) {
    #pragma unroll
    for (int reg = 0; reg < 4; reg++) {
      const int rl = i * 16 + quad * 4 + reg;
      const float iz = hZ[rl];
      const float p0 = exp2f(s[i][0][reg] * iz);
      const float p1 = exp2f(s[i][1][reg] * iz);
      const float p2 = exp2f(s[i][2][reg] * iz);
      const float p3 = exp2f(s[i][3][reg] * iz);
      float zp = (p0 + p1) + (p2 + p3);
      zp = rowsum16(zp);
      if (lm == 0) hP[wsl][rl] = zp;
      uint32_t o = __builtin_amdgcn_cvt_pk_fp8_f32(p0, p1, 0, false);
      o = __builtin_amdgcn_cvt_pk_fp8_f32(p2, p3, o, true);
      *(uint32_t*)(P8 + (size_t)(m0 + rl) * NTOK + c * CHK + pbyte) = o;
    }
  }
  __syncthreads();
  if (tid < 64) {
    float t = 0.f;
    #pragma unroll
    for (int w2 = 0; w2 < 8; w2++) t += hP[w2][tid];
    atomicAdd(&lsum[m0 + tid], t);
  }
}

// ---------------- cls row (exact fp32) ----------------
__global__ void cls_u_kernel(const float* __restrict__ Wk, const float* __restrict__ bk,
                             const float* __restrict__ q0g, float* __restrict__ uc) {
  __shared__ float q0[512];
  const int tid = threadIdx.x;
  q0[tid] = q0g[tid];
  q0[tid + 256] = q0g[tid + 256];
  __syncthreads();
  if (blockIdx.x < 8) {
    const int c = blockIdx.x * 64 + (tid >> 2), ii = tid & 3;
    float acc = 0.f;
    #pragma unroll 8
    for (int j = ii; j < 512; j += 4) acc += Wk[(size_t)c * 512 + j] * q0[j];
    acc += __shfl_xor(acc, 1, 64);
    acc += __shfl_xor(acc, 2, 64);
    if (ii == 0) uc[c] = acc;
  } else if (tid < 64) {
    float acc = 0.f;
    #pragma unroll 8
    for (int j = tid; j < 512; j += 64) acc += bk[j] * q0[j];
    #pragma unroll
    for (int off = 1; off < 64; off <<= 1) acc += __shfl_xor(acc, off, 64);
    if (tid == 0) uc[512] = acc;
  }
}

__global__ void cls_scores_kernel(const float* __restrict__ x, const float* __restrict__ uc,
                                  float* __restrict__ s0) {
  __shared__ float u[512];
  __shared__ float c0s;
  int tid = threadIdx.x;  // 256
  for (int i = tid; i < 512; i += 256) u[i] = uc[i];
  if (tid == 0) c0s = uc[512];
  __syncthreads();
  int rowg = blockIdx.x * 32 + (tid >> 3);
  int ii = tid & 7;
  const float* xr = x + rowg * 512;
  float acc = 0.f;
  for (int i = ii; i < 512; i += 8) acc += xr[i] * u[i];
  acc += __shfl_xor(acc, 1, 64);
  acc += __shfl_xor(acc, 2, 64);
  acc += __shfl_xor(acc, 4, 64);
  if (ii == 0) s0[rowg] = (acc + c0s) * SCL;
}

__global__ void cls_softmax_kernel(const float* __restrict__ s0, float* __restrict__ out) {
  int tid = threadIdx.x;  // 1024 = 16 waves, wave w = chunk w
  int w = tid >> 6, lane = tid & 63;
  const float* sc = s0 + w * 512;
  float v[8];
  float m = -1e30f;
  #pragma unroll
  for (int j = 0; j < 8; j++) { v[j] = sc[lane * 8 + j]; m = fmaxf(m, v[j]); }
  for (int off = 1; off < 64; off <<= 1) m = fmaxf(m, __shfl_xor(m, off, 64));
  float z = 0.f;
  #pragma unroll
  for (int j = 0; j < 8; j++) { v[j] = expf(v[j] - m); z += v[j]; }
  for (int off = 1; off < 64; off <<= 1) z += __shfl_xor(z, off, 64);
  float invz = 1.f / z;
  float l = 0.f;
  #pragma unroll
  for (int j = 0; j < 8; j++) { v[j] = expf(v[j] * invz); l += v[j]; }
  for (int off = 1; off < 64; off <<= 1) l += __shfl_xor(l, off, 64);
  __shared__ float lw[16];
  if (lane == 0) lw[w] = l;
  __syncthreads();
  float L = 0.f;
  for (int i = 0; i < 16; i++) L += lw[i];
  float invL = 1.f / L;
  #pragma unroll
  for (int j = 0; j < 8; j++) out[w * 512 + lane * 8 + j] = v[j] * invL;
}

extern "C" void kernel_launch(void* const* d_in, const int* in_sizes, int n_in,
                              void* d_out, int out_size, void* d_ws, size_t ws_size,
                              hipStream_t stream) {
  const float* x  = (const float*)d_in[0];
  const float* Wq = (const float*)d_in[1];
  const float* bq = (const float*)d_in[2];
  const float* Wk = (const float*)d_in[3];
  const float* bk = (const float*)d_in[4];
  const float* Wv = (const float*)d_in[5];
  const float* bv = (const float*)d_in[6];
  const float* Wo = (const float*)d_in[7];
  const float* bo = (const float*)d_in[8];
  float* out = (float*)d_out;

  char* ws = (char*)d_ws;
  u16* xb    = (u16*)(ws);                  // 8 MB
  u16* Wall  = (u16*)(ws + 8388608);        // 1.5 MB
  u16* WoT   = (u16*)(ws + 9961472);        // 512 KB
  u8*  qb8   = (u8*)(ws + 10485760);        // 4 MB fp8 (k-interleaved)
  u8*  kb8   = (u8*)(ws + 14680064);        // 4 MB fp8 (k-interleaved)
  u8*  vT8   = (u8*)(ws + 18874368);        // 4 MB fp8 (fperm tokens)
  u16* attnb = (u16*)(ws + 23068672);       // 8 MB
  float* q0g = (float*)(ws + 31457280);     // 512 f
  float* uc  = (float*)(ws + 31461376);     // 513 f
  float* s0  = (float*)(ws + 31465472);     // 8192 f
  float* lsum= (float*)(ws + 31498240);     // 8192 f
  u8*  P8    = (u8*)(ws + 31531008);        // 64 MB fp8 (fperm token cols)
  float* part= (float*)(ws + 98639872);     // 4 x 16 MB
  const size_t need_full = 98639872ULL + (size_t)KSPLIT * NTOK * DD * 4ULL;

  prep_kernel<<<5122, 256, 0, stream>>>(x, Wq, Wk, Wv, Wo, bq, xb, Wall, WoT, lsum, q0g);

  qkv_kernel<<<dim3(NTOK / 128, 12), 256, 0, stream>>>(xb, Wall, bq, bk, bv, qb8, kb8, vT8);

  scores_kernel<<<dim3(NTOK / 64, NCH), 512, 0, stream>>>(qb8, kb8, P8, lsum);

  if (ws_size >= need_full) {
    gemm_fp8_kernel<4><<<dim3(NTOK / 128, DD / 128, KSPLIT), 256, 0, stream>>>(
        P8, vT8, KLEN, NTOK, NTOK, part, nullptr);
    pv_reduce_kernel<<<NTOK * DD / 4 / 256, 256, 0, stream>>>(part, lsum, attnb);
  } else {
    gemm_fp8_kernel<3><<<dim3(NTOK / 128, DD / 128), 256, 0, stream>>>(
        P8, vT8, NTOK, NTOK, NTOK, attnb, lsum);
  }

  outproj_kernel<<<dim3(NTOK / 128, DD / 128), 256, 0, stream>>>(attnb, WoT, bo, out, x);

  cls_u_kernel<<<9, 256, 0, stream>>>(Wk, bk, q0g, uc);
  cls_scores_kernel<<<NTOK / 32, 256, 0, stream>>>(x, uc, s0);
  cls_softmax_kernel<<<1, 1024, 0, stream>>>(s0, out + (size_t)NTOK * DD);
}